// Round 1
// 648.531 us; speedup vs baseline: 1.0577x; 1.0577x over previous
//
#include <hip/hip_runtime.h>

// Pruned RNN-T loss forward. B=8, T=192, U=193, V=512, PRUNE=5.
// Band row t: u in [t-5, t+5] ∩ [0, tlen]; lane d <-> u = t-5+d (d in 0..10).
//
// v2: chunked (lse,+)-semiring scan over rows to kill the 193-step sequential
// latency chain (8 waves on a 256-CU chip = latency-bound, clock-sensitive).
//   Kernel 1: 8b x 16 chunks of 12 rows; each chunk's 11x11 banded transfer
//             matrix via 11 parallel 16-lane DPP engines running the SAME
//             verified row update on basis vectors. Depth: 12 rows.
//   Kernel 2: row 0 + sequential fold of 16 chunk matrices (lane-parallel
//             matvec, lae2-tree over 11 terms) -> loss.
// Per-row math identical to the previous harness-verified kernel; only chunk
// boundaries reassociate the logsumexp (few-ulp diffs).

#define NEGV -1.0e30f
#define LOG2E 1.4426950408889634f
#define LN2   0.6931471805599453f

constexpr int Bc = 8, Tc = 192, Uc = 193, Vc = 512;
constexpr int Utc = Uc - 1;   // 192
constexpr int NCH = 16;       // chunks covering rows 1..192
constexpr int CL  = 12;       // rows per chunk (16*12 == 192)

#if __has_builtin(__builtin_amdgcn_exp2f)
#define EXP2(x) __builtin_amdgcn_exp2f(x)
#else
#define EXP2(x) __expf((x) * LN2)
#endif
#if __has_builtin(__builtin_amdgcn_logf)
#define LOG2(x) __builtin_amdgcn_logf(x)
#else
#define LOG2(x) (__logf(x) * LOG2E)
#endif

// result = valid_src ? src[lane mapped by CTRL] : old   (bound_ctrl=0)
// row_shr:N (lane i <- i-N within 16-lane row): CTRL = 0x110+N
// row_shl:1 (lane i <- i+1 within row):         CTRL = 0x101
template <int CTRL>
__device__ __forceinline__ float dppf(float old, float x) {
    return __int_as_float(__builtin_amdgcn_update_dpp(
        __float_as_int(old), __float_as_int(x), CTRL, 0xF, 0xF, false));
}

// log2-domain logaddexp: values are ln(p)*log2(e); exp2(-1.4e30-x)==0 exactly.
__device__ __forceinline__ float lae2(float a, float b) {
    float m = fmaxf(a, b);
    float d = fminf(a, b) - m;
    return m + LOG2(1.0f + EXP2(d));
}

__device__ __forceinline__ float prefix_sum16(float g) {
    g += dppf<0x111>(0.0f, g);
    g += dppf<0x112>(0.0f, g);
    g += dppf<0x114>(0.0f, g);
    g += dppf<0x118>(0.0f, g);
    return g;
}

__device__ __forceinline__ float prefix_lae16(float s) {
    s = lae2(dppf<0x111>(NEGV, s), s);
    s = lae2(dppf<0x112>(NEGV, s), s);
    s = lae2(dppf<0x114>(NEGV, s), s);
    s = lae2(dppf<0x118>(NEGV, s), s);
    return s;
}

// One verified row update: alpha_{t-1} (d-coords of row t-1) -> alpha_t.
__device__ __forceinline__ float row_update(float alpha, float2 cur, int t,
                                            int tlen, int ls) {
    float base = dppf<0x101>(NEGV, alpha) + cur.x;  // blank move, band shift by 1
    float res;
    if (t == Tc) {
        res = base;                  // row T: emit gains are -inf in the reference
    } else {
        float G = prefix_sum16(cur.y);
        res = prefix_lae16(base - G) + G;  // r[d]=G[d]+prefix-lae(base[k]-G[k])
    }
    int u = t - 5 + ls;
    bool valid = (ls <= 10) && (u >= 0) && (u <= tlen);
    return valid ? res : NEGV;
}

// ---------------- Kernel 1: per-chunk 11x11 transfer matrices ----------------
// grid = Bc*NCH blocks, 192 threads = 12 sixteen-lane engines (11 used).
__global__ void __launch_bounds__(192) rnnt_chunk_kernel(
        const float* __restrict__ lp, const int* __restrict__ targets,
        const int* __restrict__ logit_len, const int* __restrict__ target_len,
        float* __restrict__ ws) {
    __shared__ float2 rowbuf[CL * 16];  // [r][d] = {blank into (t,u), emit gain} * log2e

    const int b = blockIdx.x >> 4;
    const int c = blockIdx.x & 15;
    const int llen = logit_len[b];
    const int tlen = target_len[b];
    const int t0 = 1 + c * CL;          // first row of this chunk

    // gather this chunk's band cells: one thread per (r,d)
    {
        const int idx = threadIdx.x;    // 0..191
        const int r = idx >> 4, d = idx & 15;
        const int t = t0 + r;
        if (t <= llen) {
            const int u = t - 5 + d;
            float bl = NEGV;            // blank into (t,u): lp[b,t-1,u,0]
            float g = 0.0f;             // emit into (t,u) from (t,u-1)
            if (d <= 10 && u >= 0 && u <= Uc - 1)
                bl = lp[(((size_t)b * Tc + (t - 1)) * Uc + u) * Vc] * LOG2E;
            if (d <= 10 && u >= 1 && u <= Uc - 1 && t <= Tc - 1)
                g = lp[(((size_t)b * Tc + t) * Uc + (u - 1)) * Vc
                       + targets[b * Utc + (u - 1)]] * LOG2E;
            rowbuf[idx] = make_float2(bl, g);
        }
    }
    __syncthreads();

    const int j  = threadIdx.x >> 4;    // basis-column / engine id
    const int ls = threadIdx.x & 15;    // d within the band
    if (j >= 11) return;

    // basis vector e_j in row (t0-1) coords; chunks past llen yield identity.
    float alpha = (ls == j) ? 0.0f : NEGV;
    #pragma unroll
    for (int r = 0; r < CL; ++r) {
        const int t = t0 + r;
        if (t > llen) break;
        alpha = row_update(alpha, rowbuf[r * 16 + ls], t, tlen, ls);
    }
    // column j of the chunk transfer matrix (always written: no poison reads)
    ws[(((size_t)(b * NCH + c) * 11 + j) << 4) + ls] = alpha;
}

// ---------------- Kernel 2: row 0 + sequential fold of chunk matrices -------
// grid = Bc blocks, 1 wave each.
__global__ void __launch_bounds__(64) rnnt_final_kernel(
        const float* __restrict__ lp, const int* __restrict__ targets,
        const int* __restrict__ logit_len, const int* __restrict__ target_len,
        const float* __restrict__ ws, float* __restrict__ out) {
    const int b = blockIdx.x;
    const int llen = logit_len[b];
    const int tlen = target_len[b];
    const int lane = threadIdx.x;       // 0..63
    const int ls = lane & 15;

    // row 0: alpha[0,0]=0 at u=0 (d=5), within-row emit chain
    float g = 0.0f;
    {
        const int u = ls - 5;           // t = 0
        if (ls <= 10 && u >= 1)         // u <= 10 < Uc-1, t=0 <= Tc-1 always
            g = lp[((size_t)b * Tc * Uc + (u - 1)) * Vc
                   + targets[b * Utc + (u - 1)]] * LOG2E;
    }
    float v;
    {
        float G = prefix_sum16(g);
        float base = (ls == 5) ? 0.0f : NEGV;
        float res = prefix_lae16(base - G) + G;
        const int u = ls - 5;
        const bool valid = (ls <= 10) && (u >= 0) && (u <= tlen);
        v = valid ? res : NEGV;
    }

    // v_new[d] = lse_j( M_c[d][j] + v[j] ), c = 0..15 sequentially
    for (int c = 0; c < NCH; ++c) {
        const size_t off = ((size_t)(b * NCH + c) * 11) << 4;
        float cand[11];
        #pragma unroll
        for (int jj = 0; jj < 11; ++jj) {
            float m = ws[off + ((size_t)jj << 4) + ls];
            float vj = __int_as_float(
                __builtin_amdgcn_readlane(__float_as_int(v), jj));
            cand[jj] = m + vj;
        }
        float a0 = lae2(cand[0], cand[1]);
        float a1 = lae2(cand[2], cand[3]);
        float a2 = lae2(cand[4], cand[5]);
        float a3 = lae2(cand[6], cand[7]);
        float a4 = lae2(cand[8], cand[9]);
        float b0 = lae2(a0, a1);
        float b1 = lae2(a2, a3);
        float b2 = lae2(a4, cand[10]);
        v = lae2(lae2(b0, b1), b2);
    }

    // alpha holds row llen; terminal cell u=tlen lives in lane tlen-llen+5
    if (lane == tlen - llen + 5)
        atomicAdd(out, v * (-LN2 / (float)Bc));  // back to natural log + mean
}

extern "C" void kernel_launch(void* const* d_in, const int* in_sizes, int n_in,
                              void* d_out, int out_size, void* d_ws, size_t ws_size,
                              hipStream_t stream) {
    const float* lp    = (const float*)d_in[0];
    const int* targets = (const int*)d_in[1];
    const int* llen    = (const int*)d_in[2];
    const int* tlen    = (const int*)d_in[3];
    float* out = (float*)d_out;

    // needs 8*16*11*16*4 B = 112,640 B of workspace
    hipMemsetAsync(out, 0, sizeof(float) * out_size, stream);
    rnnt_chunk_kernel<<<Bc * NCH, 192, 0, stream>>>(
        lp, targets, llen, tlen, (float*)d_ws);
    rnnt_final_kernel<<<Bc, 64, 0, stream>>>(
        lp, targets, llen, tlen, (const float*)d_ws, out);
}